// Round 1
// baseline (138.925 us; speedup 1.0000x reference)
//
#include <hip/hip_runtime.h>
#include <hip/hip_bf16.h>

// Problem: B=4096, IN=1024, H=1024.
// pre = x@U^T + h@W^T + Ub  -> gates -> h_t, c_t
// GEMM: M=4096 (batch), N=4096 (4H), K=2048 (IN+H concat)

#define BATCH 4096
#define HID   1024
#define KDIM  2048
#define NDIM  4096

#define TM 128
#define TN 128
#define TK 32

typedef __bf16 bf16x8 __attribute__((ext_vector_type(8)));
typedef float  f32x4  __attribute__((ext_vector_type(4)));

__device__ __forceinline__ void async_load16(const void* g, void* l) {
    __builtin_amdgcn_global_load_lds(
        (const __attribute__((address_space(1))) void*)g,
        (__attribute__((address_space(3))) void*)l,
        16, 0, 0);
}

// ---------------------------------------------------------------------------
// Kernel 1: f32 -> bf16 conversion + concatenation along K.
// A_cat[row][0:1024]=x[row], A_cat[row][1024:2048]=h[row]   (row in [0,4096))
// B_cat[row][0:1024]=U[row], B_cat[row][1024:2048]=W[row]
// One thread converts 8 floats (two float4 loads, one 16B store).
// ---------------------------------------------------------------------------
__global__ __launch_bounds__(256) void convert_kernel(
    const float* __restrict__ x, const float* __restrict__ h,
    const float* __restrict__ U, const float* __restrict__ W,
    __hip_bfloat16* __restrict__ Acat, __hip_bfloat16* __restrict__ Bcat)
{
    const int CH_PER_MAT = (4096 * KDIM) / 8;      // 1048576 chunks per matrix
    int idx = blockIdx.x * blockDim.x + threadIdx.x;
    bool isB = idx >= CH_PER_MAT;
    int c = isB ? (idx - CH_PER_MAT) : idx;
    int row  = c >> 8;                 // 256 chunks of 8 per 2048-wide row
    int col  = (c & 255) << 3;         // 0..2040, multiple of 8
    const float* src;
    if (col < 1024) src = (isB ? U : x) + (size_t)row * 1024 + col;
    else            src = (isB ? W : h) + (size_t)row * 1024 + (col - 1024);
    float4 v0 = *(const float4*)(src);
    float4 v1 = *(const float4*)(src + 4);
    __hip_bfloat16 tmp[8];
    tmp[0] = __float2bfloat16(v0.x); tmp[1] = __float2bfloat16(v0.y);
    tmp[2] = __float2bfloat16(v0.z); tmp[3] = __float2bfloat16(v0.w);
    tmp[4] = __float2bfloat16(v1.x); tmp[5] = __float2bfloat16(v1.y);
    tmp[6] = __float2bfloat16(v1.z); tmp[7] = __float2bfloat16(v1.w);
    __hip_bfloat16* dst = (isB ? Bcat : Acat) + (size_t)row * KDIM + col;
    *(bf16x8*)dst = *(const bf16x8*)tmp;
}

// ---------------------------------------------------------------------------
// Kernel 2: bf16 GEMM, B^T layout (both A [M][K] and B [N][K] row-major).
// m97 structure: 128x128 tile, BK=32, 256 threads = 4 waves (2x2),
// each wave owns a 64x64 sub-tile = 4x4 fragments of 16x16x32 MFMA.
// global_load_lds width=16 staging, 2 barriers per K-step.
// ---------------------------------------------------------------------------
__global__ __launch_bounds__(256) void gemm_bt_kernel(
    const __hip_bfloat16* __restrict__ A,   // [M=4096][K=2048]
    const __hip_bfloat16* __restrict__ Bm,  // [N=4096][K=2048]
    float* __restrict__ C)                  // [M][N] = pre
{
    __shared__ __align__(16) __hip_bfloat16 As[TM * TK];  // 8 KB
    __shared__ __align__(16) __hip_bfloat16 Bs[TN * TK];  // 8 KB

    const int tid  = threadIdx.x;
    const int lane = tid & 63;
    const int wave = tid >> 6;
    const int wr   = wave >> 1;   // wave row 0..1
    const int wc   = wave & 1;    // wave col 0..1

    // XCD-aware swizzle: 1024 blocks, 1024 % 8 == 0 -> bijective.
    int wg  = blockIdx.x;
    int wgs = (wg & 7) * (1024 / 8) + (wg >> 3);
    const int bm = wgs >> 5;      // 0..31
    const int bn = wgs & 31;      // 0..31

    const __hip_bfloat16* Ab = A  + (size_t)bm * TM * KDIM;
    const __hip_bfloat16* Bb = Bm + (size_t)bn * TN * KDIM;

    f32x4 acc[4][4] = {};

    // Per-lane fragment addresses (within tile)
    const int frow = lane & 15;           // fragment row/col within 16
    const int kq   = (lane >> 4) << 3;    // k offset 0/8/16/24

    for (int k0 = 0; k0 < KDIM; k0 += TK) {
        // --- stage A and B tiles: 512 chunks of 16B each, 256 threads x 2 ---
#pragma unroll
        for (int q = 0; q < 2; ++q) {
            int ch = q * 256 + wave * 64 + lane;     // LDS dest = base + lane*16 (wave-uniform OK)
            int row = ch >> 2;                       // 4 chunks per 32-wide row
            int col = (ch & 3) << 3;
            async_load16(Ab + (size_t)row * KDIM + k0 + col, &As[ch * 8]);
        }
#pragma unroll
        for (int q = 0; q < 2; ++q) {
            int ch = q * 256 + wave * 64 + lane;
            int row = ch >> 2;
            int col = (ch & 3) << 3;
            async_load16(Bb + (size_t)row * KDIM + k0 + col, &Bs[ch * 8]);
        }
        __syncthreads();   // drains vmcnt (compiler emits full waitcnt before barrier)

        // --- fragments + MFMA ---
        bf16x8 af[4], bfr[4];
#pragma unroll
        for (int m = 0; m < 4; ++m)
            af[m] = *(const bf16x8*)&As[(wr * 64 + m * 16 + frow) * TK + kq];
#pragma unroll
        for (int n = 0; n < 4; ++n)
            bfr[n] = *(const bf16x8*)&Bs[(wc * 64 + n * 16 + frow) * TK + kq];
#pragma unroll
        for (int m = 0; m < 4; ++m)
#pragma unroll
            for (int n = 0; n < 4; ++n)
                acc[m][n] = __builtin_amdgcn_mfma_f32_16x16x32_bf16(af[m], bfr[n], acc[m][n], 0, 0, 0);
        __syncthreads();
    }

    // --- epilogue: C/D layout col=lane&15, row=(lane>>4)*4+reg ---
    const int orow = bm * TM + wr * 64 + ((lane >> 4) << 2);
    const int ocol = bn * TN + wc * 64 + (lane & 15);
#pragma unroll
    for (int m = 0; m < 4; ++m)
#pragma unroll
        for (int n = 0; n < 4; ++n)
#pragma unroll
            for (int r = 0; r < 4; ++r)
                C[(size_t)(orow + m * 16 + r) * NDIM + ocol + n * 16] = acc[m][n][r];
}

// ---------------------------------------------------------------------------
// Kernel 3: gates + state update. float4-vectorized, memory-bound.
// out[0 : B*H)        = h_t
// out[B*H : 2*B*H)    = c_t
// ---------------------------------------------------------------------------
__device__ __forceinline__ float sigmoidf_(float v) {
    return 1.0f / (1.0f + __expf(-v));
}
__device__ __forceinline__ float tanhf_(float v) {
    return 1.0f - 2.0f / (__expf(2.0f * v) + 1.0f);
}

__global__ __launch_bounds__(256) void gates_kernel(
    const float* __restrict__ pre, const float* __restrict__ Ub,
    const float* __restrict__ c_prev, float* __restrict__ out)
{
    int i = blockIdx.x * blockDim.x + threadIdx.x;   // float4 index, B*H/4 total
    int b = i >> 8;                // 256 float4 per 1024-wide row
    int j = (i & 255) << 2;
    const float* p = pre + (size_t)b * NDIM;
    float4 fp = *(const float4*)(p + j);
    float4 ip = *(const float4*)(p + 1024 + j);
    float4 op = *(const float4*)(p + 2048 + j);
    float4 gp = *(const float4*)(p + 3072 + j);
    float4 bf = *(const float4*)(Ub + j);
    float4 bi = *(const float4*)(Ub + 1024 + j);
    float4 bo = *(const float4*)(Ub + 2048 + j);
    float4 bg = *(const float4*)(Ub + 3072 + j);
    float4 cp = *(const float4*)(c_prev + (size_t)b * HID + j);

    float4 hv, cv;
    {
        float f = sigmoidf_(fp.x + bf.x), it = sigmoidf_(ip.x + bi.x);
        float o = sigmoidf_(op.x + bo.x), g  = tanhf_(gp.x + bg.x);
        cv.x = f * cp.x + it * g; hv.x = o * tanhf_(cv.x);
    }
    {
        float f = sigmoidf_(fp.y + bf.y), it = sigmoidf_(ip.y + bi.y);
        float o = sigmoidf_(op.y + bo.y), g  = tanhf_(gp.y + bg.y);
        cv.y = f * cp.y + it * g; hv.y = o * tanhf_(cv.y);
    }
    {
        float f = sigmoidf_(fp.z + bf.z), it = sigmoidf_(ip.z + bi.z);
        float o = sigmoidf_(op.z + bo.z), g  = tanhf_(gp.z + bg.z);
        cv.z = f * cp.z + it * g; hv.z = o * tanhf_(cv.z);
    }
    {
        float f = sigmoidf_(fp.w + bf.w), it = sigmoidf_(ip.w + bi.w);
        float o = sigmoidf_(op.w + bo.w), g  = tanhf_(gp.w + bg.w);
        cv.w = f * cp.w + it * g; hv.w = o * tanhf_(cv.w);
    }

    float* hout = out + (size_t)b * HID + j;
    float* cout_ = out + (size_t)BATCH * HID + (size_t)b * HID + j;
    *(float4*)hout = hv;
    *(float4*)cout_ = cv;
}

// ---------------------------------------------------------------------------
extern "C" void kernel_launch(void* const* d_in, const int* in_sizes, int n_in,
                              void* d_out, int out_size, void* d_ws, size_t ws_size,
                              hipStream_t stream) {
    const float* x      = (const float*)d_in[0];
    const float* h_prev = (const float*)d_in[1];
    const float* c_prev = (const float*)d_in[2];
    const float* U_w    = (const float*)d_in[3];
    const float* U_b    = (const float*)d_in[4];
    const float* W_w    = (const float*)d_in[5];
    float* out = (float*)d_out;

    char* ws = (char*)d_ws;
    __hip_bfloat16* Acat = (__hip_bfloat16*)ws;                      // 16 MB
    __hip_bfloat16* Bcat = (__hip_bfloat16*)(ws + (16u << 20));      // 16 MB
    float*          pre  = (float*)(ws + (32u << 20));               // 64 MB

    // 2 * (4096*2048/8) chunks / 256 threads = 8192 blocks
    convert_kernel<<<8192, 256, 0, stream>>>(x, h_prev, U_w, W_w, Acat, Bcat);
    // (4096/128) * (4096/128) = 1024 blocks
    gemm_bt_kernel<<<1024, 256, 0, stream>>>(Acat, Bcat, pre);
    // 4096*1024/4 float4 / 256 = 4096 blocks
    gates_kernel<<<4096, 256, 0, stream>>>(pre, U_b, c_prev, out);
}

// Round 2
// 104.554 us; speedup vs baseline: 1.3287x; 1.3287x over previous
//
#include <hip/hip_runtime.h>
#include <hip/hip_bf16.h>

// Problem: B=4096, IN=1024, H=1024.
// pre = x@U^T + h@W^T + Ub  -> gates -> h_t, c_t
// GEMM: M=4096 (batch), N=4096 (4H), K=2048 (IN+H concat)

#define BATCH 4096
#define HID   1024
#define KDIM  2048
#define NDIM  4096

// 256x256 tile, BK=32, 4-slot LDS ring, 8 waves (2Mx4N), 512 threads.
#define BM 256
#define BN 256
#define BK 32
#define NT (KDIM / BK)          // 64 K-tiles
#define SLOT_E (BM * BK)        // 8192 bf16 elements per A/B slot

typedef __bf16 bf16x8 __attribute__((ext_vector_type(8)));
typedef float  f32x4  __attribute__((ext_vector_type(4)));

__device__ __forceinline__ void async_load16(const void* g, void* l) {
    __builtin_amdgcn_global_load_lds(
        (const __attribute__((address_space(1))) void*)g,
        (__attribute__((address_space(3))) void*)l,
        16, 0, 0);
}

// ---------------------------------------------------------------------------
// Kernel 1: f32 -> bf16 conversion + concatenation along K. (unchanged)
// ---------------------------------------------------------------------------
__global__ __launch_bounds__(256) void convert_kernel(
    const float* __restrict__ x, const float* __restrict__ h,
    const float* __restrict__ U, const float* __restrict__ W,
    __hip_bfloat16* __restrict__ Acat, __hip_bfloat16* __restrict__ Bcat)
{
    const int CH_PER_MAT = (4096 * KDIM) / 8;
    int idx = blockIdx.x * blockDim.x + threadIdx.x;
    bool isB = idx >= CH_PER_MAT;
    int c = isB ? (idx - CH_PER_MAT) : idx;
    int row  = c >> 8;
    int col  = (c & 255) << 3;
    const float* src;
    if (col < 1024) src = (isB ? U : x) + (size_t)row * 1024 + col;
    else            src = (isB ? W : h) + (size_t)row * 1024 + (col - 1024);
    float4 v0 = *(const float4*)(src);
    float4 v1 = *(const float4*)(src + 4);
    __hip_bfloat16 tmp[8];
    tmp[0] = __float2bfloat16(v0.x); tmp[1] = __float2bfloat16(v0.y);
    tmp[2] = __float2bfloat16(v0.z); tmp[3] = __float2bfloat16(v0.w);
    tmp[4] = __float2bfloat16(v1.x); tmp[5] = __float2bfloat16(v1.y);
    tmp[6] = __float2bfloat16(v1.z); tmp[7] = __float2bfloat16(v1.w);
    __hip_bfloat16* dst = (isB ? Bcat : Acat) + (size_t)row * KDIM + col;
    *(bf16x8*)dst = *(const bf16x8*)tmp;
}

// ---------------------------------------------------------------------------
// Kernel 2: bf16 GEMM, B^T layout, deep-pipelined 256^2 schedule.
//  - 4-slot LDS ring (128 KB), K-tile t in slot t&3; stage K(t+3) during t.
//  - Counted vmcnt(8) once per K-tile (2 K-tiles of loads stay in flight).
//  - T2 XOR swizzle: physical 16B slot sp = sg ^ ((row>>1)&3); linear LDS
//    dest (global_load_lds) + pre-swizzled global source + swizzled ds_read.
//  - 2 phases/K-tile: {ds_read || 2 stage -> barrier -> setprio -> 16 MFMA
//    -> setprio -> barrier}; vmcnt(8) before phase-2's closing barrier.
// ---------------------------------------------------------------------------
__global__ __launch_bounds__(512, 2) void gemm_bt_kernel(
    const __hip_bfloat16* __restrict__ A,   // [4096][2048]
    const __hip_bfloat16* __restrict__ Bm,  // [4096][2048]
    float* __restrict__ C)                  // [4096][4096] = pre
{
    __shared__ __align__(16) __hip_bfloat16 smem[4 * 2 * SLOT_E];  // 128 KB

    const int tid  = threadIdx.x;
    const int lane = tid & 63;
    const int wid  = tid >> 6;     // 0..7
    const int wm   = wid >> 2;     // 0..1  (M half)
    const int wn   = wid & 3;      // 0..3  (N quarter)

    // XCD-aware swizzle: 256 blocks, 256 % 8 == 0 -> bijective.
    int wg  = blockIdx.x;
    int wgs = (wg & 7) * (256 / 8) + (wg >> 3);
    const int bm = wgs >> 4;       // 16x16 block grid
    const int bn = wgs & 15;

    const __hip_bfloat16* Ab = A  + (size_t)bm * BM * KDIM;
    const __hip_bfloat16* Bb = Bm + (size_t)bn * BN * KDIM;

    // ds_read fragment addressing (swizzled).
    const int frow = lane & 15;
    const int sp8  = (((lane >> 4) ^ ((frow >> 1) & 3)) << 3);  // element offset
    const int arow = wm * 128 + frow;
    const int brow = wn * 64  + frow;

    // Staging: 1024 16B-chunks per matrix per K-tile; thread stages chunks
    // c0=tid, c1=512+tid. LDS dest linear (chunk c -> bytes c*16);
    // global source pre-swizzled: sg = sp ^ ((row>>1)&3).
    const int c0 = tid,        c1 = 512 + tid;
    const int r0 = c0 >> 2,    r1 = c1 >> 2;
    const int g0 = ((c0 & 3) ^ ((r0 >> 1) & 3)) << 3;  // element offset in row
    const int g1 = ((c1 & 3) ^ ((r1 >> 1) & 3)) << 3;
    const size_t ga0 = (size_t)r0 * KDIM + g0;
    const size_t ga1 = (size_t)r1 * KDIM + g1;
    const int l0 = c0 << 3,    l1 = c1 << 3;           // LDS element offsets

    f32x4 acc[8][4] = {};

#define STAGE_A(kt, slot) do { \
    int _ko = (kt) * BK; unsigned _b = (unsigned)((slot) * 2 + 0) * SLOT_E; \
    async_load16(Ab + ga0 + _ko, &smem[_b + l0]); \
    async_load16(Ab + ga1 + _ko, &smem[_b + l1]); } while (0)
#define STAGE_B(kt, slot) do { \
    int _ko = (kt) * BK; unsigned _b = (unsigned)((slot) * 2 + 1) * SLOT_E; \
    async_load16(Bb + ga0 + _ko, &smem[_b + l0]); \
    async_load16(Bb + ga1 + _ko, &smem[_b + l1]); } while (0)

    // ---- prologue: stage K0..K2, guarantee K0 landed (4 oldest of 12) ----
    STAGE_A(0, 0); STAGE_B(0, 0);
    STAGE_A(1, 1); STAGE_B(1, 1);
    STAGE_A(2, 2); STAGE_B(2, 2);
    asm volatile("s_waitcnt vmcnt(8)" ::: "memory");
    __builtin_amdgcn_s_barrier();

    for (int t = 0; t < NT; ++t) {
        const int slot = t & 3;
        const unsigned ab = (unsigned)(slot * 2 + 0) * SLOT_E;
        const unsigned bb = (unsigned)(slot * 2 + 1) * SLOT_E;
        int tp = t + 3; if (tp > NT - 1) tp = NT - 1;   // clamp: keeps vmcnt
        const int ps = (t + 3) & 3;                      // counts exact

        // ---------------- phase 1: m=0..3 x n=0..3 ----------------
        bf16x8 ar[4], br[4];
#pragma unroll
        for (int m = 0; m < 4; ++m)
            ar[m] = *(const bf16x8*)&smem[ab + (unsigned)((arow + m * 16) * BK) + sp8];
#pragma unroll
        for (int n = 0; n < 4; ++n)
            br[n] = *(const bf16x8*)&smem[bb + (unsigned)((brow + n * 16) * BK) + sp8];
        STAGE_A(tp, ps);
        __builtin_amdgcn_s_barrier();
        __builtin_amdgcn_s_setprio(1);
#pragma unroll
        for (int m = 0; m < 4; ++m)
#pragma unroll
            for (int n = 0; n < 4; ++n)
                acc[m][n] = __builtin_amdgcn_mfma_f32_16x16x32_bf16(ar[m], br[n], acc[m][n], 0, 0, 0);
        __builtin_amdgcn_s_setprio(0);
        __builtin_amdgcn_s_barrier();

        // ---------------- phase 2: m=4..7 x n=0..3 (reuse br) ----------------
        bf16x8 ar2[4];
#pragma unroll
        for (int m = 0; m < 4; ++m)
            ar2[m] = *(const bf16x8*)&smem[ab + (unsigned)((arow + 64 + m * 16) * BK) + sp8];
        STAGE_B(tp, ps);
        __builtin_amdgcn_s_barrier();
        __builtin_amdgcn_s_setprio(1);
#pragma unroll
        for (int m = 0; m < 4; ++m)
#pragma unroll
            for (int n = 0; n < 4; ++n)
                acc[m + 4][n] = __builtin_amdgcn_mfma_f32_16x16x32_bf16(ar2[m], br[n], acc[m + 4][n], 0, 0, 0);
        __builtin_amdgcn_s_setprio(0);
        // counted wait: K(t+1) fully staged; K(t+2),K(t+3) stay in flight.
        asm volatile("s_waitcnt vmcnt(8)" ::: "memory");
        __builtin_amdgcn_s_barrier();
    }
#undef STAGE_A
#undef STAGE_B

    // ---- epilogue: C/D layout col=lane&15, row=(lane>>4)*4+reg ----
    const int orow0 = bm * BM + wm * 128 + ((lane >> 4) << 2);
    const int ocol0 = bn * BN + wn * 64 + (lane & 15);
#pragma unroll
    for (int m = 0; m < 8; ++m)
#pragma unroll
        for (int n = 0; n < 4; ++n)
#pragma unroll
            for (int r = 0; r < 4; ++r)
                C[(size_t)(orow0 + m * 16 + r) * NDIM + ocol0 + n * 16] = acc[m][n][r];
}

// ---------------------------------------------------------------------------
// Kernel 3: gates + state update. (unchanged)
// ---------------------------------------------------------------------------
__device__ __forceinline__ float sigmoidf_(float v) {
    return 1.0f / (1.0f + __expf(-v));
}
__device__ __forceinline__ float tanhf_(float v) {
    return 1.0f - 2.0f / (__expf(2.0f * v) + 1.0f);
}

__global__ __launch_bounds__(256) void gates_kernel(
    const float* __restrict__ pre, const float* __restrict__ Ub,
    const float* __restrict__ c_prev, float* __restrict__ out)
{
    int i = blockIdx.x * blockDim.x + threadIdx.x;
    int b = i >> 8;
    int j = (i & 255) << 2;
    const float* p = pre + (size_t)b * NDIM;
    float4 fp = *(const float4*)(p + j);
    float4 ip = *(const float4*)(p + 1024 + j);
    float4 op = *(const float4*)(p + 2048 + j);
    float4 gp = *(const float4*)(p + 3072 + j);
    float4 bf = *(const float4*)(Ub + j);
    float4 bi = *(const float4*)(Ub + 1024 + j);
    float4 bo = *(const float4*)(Ub + 2048 + j);
    float4 bg = *(const float4*)(Ub + 3072 + j);
    float4 cp = *(const float4*)(c_prev + (size_t)b * HID + j);

    float4 hv, cv;
    {
        float f = sigmoidf_(fp.x + bf.x), it = sigmoidf_(ip.x + bi.x);
        float o = sigmoidf_(op.x + bo.x), g  = tanhf_(gp.x + bg.x);
        cv.x = f * cp.x + it * g; hv.x = o * tanhf_(cv.x);
    }
    {
        float f = sigmoidf_(fp.y + bf.y), it = sigmoidf_(ip.y + bi.y);
        float o = sigmoidf_(op.y + bo.y), g  = tanhf_(gp.y + bg.y);
        cv.y = f * cp.y + it * g; hv.y = o * tanhf_(cv.y);
    }
    {
        float f = sigmoidf_(fp.z + bf.z), it = sigmoidf_(ip.z + bi.z);
        float o = sigmoidf_(op.z + bo.z), g  = tanhf_(gp.z + bg.z);
        cv.z = f * cp.z + it * g; hv.z = o * tanhf_(cv.z);
    }
    {
        float f = sigmoidf_(fp.w + bf.w), it = sigmoidf_(ip.w + bi.w);
        float o = sigmoidf_(op.w + bo.w), g  = tanhf_(gp.w + bg.w);
        cv.w = f * cp.w + it * g; hv.w = o * tanhf_(cv.w);
    }

    float* hout = out + (size_t)b * HID + j;
    float* cout_ = out + (size_t)BATCH * HID + (size_t)b * HID + j;
    *(float4*)hout = hv;
    *(float4*)cout_ = cv;
}

// ---------------------------------------------------------------------------
extern "C" void kernel_launch(void* const* d_in, const int* in_sizes, int n_in,
                              void* d_out, int out_size, void* d_ws, size_t ws_size,
                              hipStream_t stream) {
    const float* x      = (const float*)d_in[0];
    const float* h_prev = (const float*)d_in[1];
    const float* c_prev = (const float*)d_in[2];
    const float* U_w    = (const float*)d_in[3];
    const float* U_b    = (const float*)d_in[4];
    const float* W_w    = (const float*)d_in[5];
    float* out = (float*)d_out;

    char* ws = (char*)d_ws;
    __hip_bfloat16* Acat = (__hip_bfloat16*)ws;                      // 16 MB
    __hip_bfloat16* Bcat = (__hip_bfloat16*)(ws + (16u << 20));      // 16 MB
    float*          pre  = (float*)(ws + (32u << 20));               // 64 MB

    convert_kernel<<<8192, 256, 0, stream>>>(x, h_prev, U_w, W_w, Acat, Bcat);
    // (4096/256) * (4096/256) = 256 blocks of 512 threads
    gemm_bt_kernel<<<256, 512, 0, stream>>>(Acat, Bcat, pre);
    gates_kernel<<<4096, 256, 0, stream>>>(pre, U_b, c_prev, out);
}

// Round 3
// 91.036 us; speedup vs baseline: 1.5260x; 1.1485x over previous
//
#include <hip/hip_runtime.h>
#include <hip/hip_bf16.h>

// Problem: B=4096, IN=1024, H=1024.
// pre = x@U^T + h@W^T + Ub -> gates -> h_t, c_t   (all fused after convert)
// GEMM: M=4096 (batch), N=4096 (4H permuted), K=2048 (IN+H concat)
//
// B-permutation: permuted column p = bn*256 + wn*64 + g*16 + c corresponds to
// gate g (f,i,o,g), hidden j = bn*64 + wn*16 + c. With the verified C/D
// layout (col = lane&15), wave fragment n == gate n at the SAME lane (same j),
// so the LSTM gate math is lane-local in the GEMM epilogue.

#define BATCH 4096
#define HID   1024
#define KDIM  2048

// 256x256 tile, BK=32, 4-slot LDS ring, 8 waves (2Mx4N), 512 threads.
#define BM 256
#define BN 256
#define BK 32
#define NT (KDIM / BK)          // 64 K-tiles
#define SLOT_E (BM * BK)        // 8192 bf16 elements per A/B slot

typedef __bf16 bf16x8 __attribute__((ext_vector_type(8)));
typedef float  f32x4  __attribute__((ext_vector_type(4)));

__device__ __forceinline__ void async_load16(const void* g, void* l) {
    __builtin_amdgcn_global_load_lds(
        (const __attribute__((address_space(1))) void*)g,
        (__attribute__((address_space(3))) void*)l,
        16, 0, 0);
}

__device__ __forceinline__ float sigmoidf_(float v) {
    return 1.0f / (1.0f + __expf(-v));
}
__device__ __forceinline__ float tanhf_(float v) {
    return 1.0f - 2.0f / (__expf(2.0f * v) + 1.0f);
}

// ---------------------------------------------------------------------------
// Kernel 1: f32 -> bf16 conversion + K-concat; B side also gate-permuted.
// A_cat[row] = [x[row] | h[row]]                       (row = batch index)
// B_cat[p]   = [U[orig] | W[orig]],  orig = g*1024 + j derived from p.
// ---------------------------------------------------------------------------
__global__ __launch_bounds__(256) void convert_kernel(
    const float* __restrict__ x, const float* __restrict__ h,
    const float* __restrict__ U, const float* __restrict__ W,
    __hip_bfloat16* __restrict__ Acat, __hip_bfloat16* __restrict__ Bcat)
{
    const int CH_PER_MAT = (4096 * KDIM) / 8;
    int idx = blockIdx.x * blockDim.x + threadIdx.x;
    bool isB = idx >= CH_PER_MAT;
    int c = isB ? (idx - CH_PER_MAT) : idx;
    int row  = c >> 8;                 // dest row (permuted for B)
    int col  = (c & 255) << 3;
    int srow = row;
    if (isB) {
        // p = bn*256 + wn*64 + g*16 + cc  ->  orig row = g*1024 + (bn*64+wn*16+cc)
        int g  = (row >> 4) & 3;
        int j  = ((row >> 8) << 6) + (((row >> 6) & 3) << 4) + (row & 15);
        srow = g * 1024 + j;
    }
    const float* src;
    if (col < 1024) src = (isB ? U : x) + (size_t)srow * 1024 + col;
    else            src = (isB ? W : h) + (size_t)srow * 1024 + (col - 1024);
    float4 v0 = *(const float4*)(src);
    float4 v1 = *(const float4*)(src + 4);
    __hip_bfloat16 tmp[8];
    tmp[0] = __float2bfloat16(v0.x); tmp[1] = __float2bfloat16(v0.y);
    tmp[2] = __float2bfloat16(v0.z); tmp[3] = __float2bfloat16(v0.w);
    tmp[4] = __float2bfloat16(v1.x); tmp[5] = __float2bfloat16(v1.y);
    tmp[6] = __float2bfloat16(v1.z); tmp[7] = __float2bfloat16(v1.w);
    __hip_bfloat16* dst = (isB ? Bcat : Acat) + (size_t)row * KDIM + col;
    *(bf16x8*)dst = *(const bf16x8*)tmp;
}

// ---------------------------------------------------------------------------
// Kernel 2: fused bf16 GEMM + LSTM gates.  Same verified 4-slot ring
// schedule as round 2 (vmcnt(8)/K-tile, T2 swizzle, 2 phases); STAGE issue
// hoisted before ds_reads; epilogue computes gates lane-locally and writes
// h_t / c_t directly (no pre buffer).
// ---------------------------------------------------------------------------
__global__ __launch_bounds__(512, 2) void gemm_lstm_kernel(
    const __hip_bfloat16* __restrict__ A,   // [4096][2048]
    const __hip_bfloat16* __restrict__ Bm,  // [4096][2048] gate-permuted
    const float* __restrict__ Ub,           // [4096]
    const float* __restrict__ c_prev,       // [4096][1024]
    float* __restrict__ out)                // h_t [4096][1024] ++ c_t [4096][1024]
{
    __shared__ __align__(16) __hip_bfloat16 smem[4 * 2 * SLOT_E];  // 128 KB

    const int tid  = threadIdx.x;
    const int lane = tid & 63;
    const int wid  = tid >> 6;     // 0..7
    const int wm   = wid >> 2;     // 0..1  (M half)
    const int wn   = wid & 3;      // 0..3  (N quarter)

    // XCD-aware swizzle: 256 blocks, 256 % 8 == 0 -> bijective.
    int wg  = blockIdx.x;
    int wgs = (wg & 7) * (256 / 8) + (wg >> 3);
    const int bm = wgs >> 4;
    const int bn = wgs & 15;

    const __hip_bfloat16* Ab = A  + (size_t)bm * BM * KDIM;
    const __hip_bfloat16* Bb = Bm + (size_t)bn * BN * KDIM;

    // ds_read fragment addressing (T2-swizzled).
    const int frow = lane & 15;
    const int sp8  = (((lane >> 4) ^ ((frow >> 1) & 3)) << 3);
    const int arow = wm * 128 + frow;
    const int brow = wn * 64  + frow;

    // Staging: 1024 16B-chunks/matrix/K-tile; linear LDS dest, pre-swizzled
    // global source (both-sides-or-neither rule).
    const int c0 = tid,        c1 = 512 + tid;
    const int r0 = c0 >> 2,    r1 = c1 >> 2;
    const int g0 = ((c0 & 3) ^ ((r0 >> 1) & 3)) << 3;
    const int g1 = ((c1 & 3) ^ ((r1 >> 1) & 3)) << 3;
    const size_t ga0 = (size_t)r0 * KDIM + g0;
    const size_t ga1 = (size_t)r1 * KDIM + g1;
    const int l0 = c0 << 3,    l1 = c1 << 3;

    f32x4 acc[8][4] = {};

#define STAGE_A(kt, slot) do { \
    int _ko = (kt) * BK; unsigned _b = (unsigned)((slot) * 2 + 0) * SLOT_E; \
    async_load16(Ab + ga0 + _ko, &smem[_b + l0]); \
    async_load16(Ab + ga1 + _ko, &smem[_b + l1]); } while (0)
#define STAGE_B(kt, slot) do { \
    int _ko = (kt) * BK; unsigned _b = (unsigned)((slot) * 2 + 1) * SLOT_E; \
    async_load16(Bb + ga0 + _ko, &smem[_b + l0]); \
    async_load16(Bb + ga1 + _ko, &smem[_b + l1]); } while (0)

    // ---- prologue: stage K0..K2; vmcnt(8) completes K0 (4 oldest of 12) ----
    STAGE_A(0, 0); STAGE_B(0, 0);
    STAGE_A(1, 1); STAGE_B(1, 1);
    STAGE_A(2, 2); STAGE_B(2, 2);
    asm volatile("s_waitcnt vmcnt(8)" ::: "memory");
    __builtin_amdgcn_s_barrier();

    for (int t = 0; t < NT; ++t) {
        const int slot = t & 3;
        const unsigned ab = (unsigned)(slot * 2 + 0) * SLOT_E;
        const unsigned bb = (unsigned)(slot * 2 + 1) * SLOT_E;
        int tp = t + 3; if (tp > NT - 1) tp = NT - 1;   // clamp keeps vmcnt exact
        const int ps = (t + 3) & 3;

        // ---------------- phase 1: m=0..3 x n=0..3 ----------------
        STAGE_A(tp, ps);
        bf16x8 ar[4], br[4];
#pragma unroll
        for (int m = 0; m < 4; ++m)
            ar[m] = *(const bf16x8*)&smem[ab + (unsigned)((arow + m * 16) * BK) + sp8];
#pragma unroll
        for (int n = 0; n < 4; ++n)
            br[n] = *(const bf16x8*)&smem[bb + (unsigned)((brow + n * 16) * BK) + sp8];
        __builtin_amdgcn_s_barrier();
        __builtin_amdgcn_s_setprio(1);
#pragma unroll
        for (int m = 0; m < 4; ++m)
#pragma unroll
            for (int n = 0; n < 4; ++n)
                acc[m][n] = __builtin_amdgcn_mfma_f32_16x16x32_bf16(ar[m], br[n], acc[m][n], 0, 0, 0);
        __builtin_amdgcn_s_setprio(0);
        __builtin_amdgcn_s_barrier();

        // ---------------- phase 2: m=4..7 x n=0..3 (reuse br) ----------------
        STAGE_B(tp, ps);
        bf16x8 ar2[4];
#pragma unroll
        for (int m = 0; m < 4; ++m)
            ar2[m] = *(const bf16x8*)&smem[ab + (unsigned)((arow + 64 + m * 16) * BK) + sp8];
        __builtin_amdgcn_s_barrier();
        __builtin_amdgcn_s_setprio(1);
#pragma unroll
        for (int m = 0; m < 4; ++m)
#pragma unroll
            for (int n = 0; n < 4; ++n)
                acc[m + 4][n] = __builtin_amdgcn_mfma_f32_16x16x32_bf16(ar2[m], br[n], acc[m + 4][n], 0, 0, 0);
        __builtin_amdgcn_s_setprio(0);
        // counted wait: K(t+1) fully staged; K(t+2),K(t+3) stay in flight.
        asm volatile("s_waitcnt vmcnt(8)" ::: "memory");
        __builtin_amdgcn_s_barrier();
    }
#undef STAGE_A
#undef STAGE_B

    // ---- fused epilogue: gates are lane-local thanks to B permutation ----
    // acc[m][g][r]: row = bm*256+wm*128+m*16+(lane>>4)*4+r,
    //               hidden j = bn*64+wn*16+(lane&15), gate g in {f,i,o,g}.
    const int j = bn * 64 + wn * 16 + (lane & 15);
    const float bf_ = Ub[j];
    const float bi_ = Ub[1024 + j];
    const float bo_ = Ub[2048 + j];
    const float bg_ = Ub[3072 + j];
    const int row0 = bm * BM + wm * 128 + ((lane >> 4) << 2);
#pragma unroll
    for (int m = 0; m < 8; ++m) {
#pragma unroll
        for (int r = 0; r < 4; ++r) {
            const int row = row0 + m * 16 + r;
            const float cp = c_prev[(size_t)row * HID + j];
            const float f  = sigmoidf_(acc[m][0][r] + bf_);
            const float it = sigmoidf_(acc[m][1][r] + bi_);
            const float o  = sigmoidf_(acc[m][2][r] + bo_);
            const float gg = tanhf_(acc[m][3][r] + bg_);
            const float cv = f * cp + it * gg;
            const float hv = o * tanhf_(cv);
            out[(size_t)row * HID + j] = hv;
            out[(size_t)BATCH * HID + (size_t)row * HID + j] = cv;
        }
    }
}

// ---------------------------------------------------------------------------
extern "C" void kernel_launch(void* const* d_in, const int* in_sizes, int n_in,
                              void* d_out, int out_size, void* d_ws, size_t ws_size,
                              hipStream_t stream) {
    const float* x      = (const float*)d_in[0];
    const float* h_prev = (const float*)d_in[1];
    const float* c_prev = (const float*)d_in[2];
    const float* U_w    = (const float*)d_in[3];
    const float* U_b    = (const float*)d_in[4];
    const float* W_w    = (const float*)d_in[5];
    float* out = (float*)d_out;

    char* ws = (char*)d_ws;
    __hip_bfloat16* Acat = (__hip_bfloat16*)ws;                      // 16 MB
    __hip_bfloat16* Bcat = (__hip_bfloat16*)(ws + (16u << 20));      // 16 MB

    convert_kernel<<<8192, 256, 0, stream>>>(x, h_prev, U_w, W_w, Acat, Bcat);
    gemm_lstm_kernel<<<256, 512, 0, stream>>>(Acat, Bcat, U_b, c_prev, out);
}